// Round 6
// baseline (948.982 us; speedup 1.0000x reference)
//
#include <hip/hip_runtime.h>

// 4D conv net, MI355X. S=30, B=2, ch 1->10->10->1, kernel 3^4, pad 1, ReLU.
// out = net(x,w) + net(x,w_swap), w_swap has (k1,k2)<->(k3,k4).
// R6: barrier-free MFMA conv. Activations live in ws as padded planes
// [h'(32)][t'(32)][c(16)] bf16 (32 B/pos, halos + c10..15 zero). A-fragments
// (K = 16*k4+c) are single aligned global_load_dwordx4 -- no LDS, no
// __syncthreads in the conv kernels. Branch-sequential buffering (118 MB ws).

static constexpr int S  = 30;
static constexpr int S2 = 900;
static constexpr long S4 = 810000;
static constexpr size_t PLANE = 32768;     // 32 h' * 32 t' * 16 c * 2 B
static constexpr size_t YBYTES = (size_t)1800 * PLANE;  // [b(2)][g1][g2]

typedef __bf16 bf16x8 __attribute__((ext_vector_type(8)));
typedef float  f32x4  __attribute__((ext_vector_type(4)));
typedef unsigned int  u32;
typedef unsigned short u16;

static __device__ __forceinline__ u16 f2bf(float f) {
    u32 u = __builtin_bit_cast(u32, f);
    return (u16)((u + 0x7fffu + ((u >> 16) & 1u)) >> 16);
}

// ---------------------------------------------------------------------------
// B-fragment table: [set(4)][k12(9)][k3(3)][tb(2)][lane(64)] uint4.
// set 0/1: layer2 br0/br1 (COUT=10); set 2/3: layer3 br0/br1 (COUT=1).
// tb=0: k = 16*k4 + c, k4 in {0,1}; tb=1: k = c for k4=2 (k<16), upper zero.
// B[k][n]: lane n + 16q holds k = q*8 + j.
__global__ __launch_bounds__(256) void fragprep_k(u32* __restrict__ ft,
    const float* __restrict__ w2, const float* __restrict__ w3)
{
    const int gid = blockIdx.x * 256 + threadIdx.x;   // 13824 total
    const int lane = gid & 63;
    int r = gid >> 6;
    const int tb = r & 1; r >>= 1;
    const int k3 = r % 3; r /= 3;
    const int k12 = r % 9; const int set = r / 9;
    const int k1 = k12 / 3, k2 = k12 % 3;
    const int n = lane & 15, q = lane >> 4;
    const int COUT = (set < 2) ? 10 : 1;
    const int swap = set & 1;
    const float* W = (set < 2) ? w2 : w3;

    u16 us[8];
#pragma unroll
    for (int j = 0; j < 8; ++j) {
        const int k = q * 8 + j;
        int k4, c; bool valid;
        if (!tb) { k4 = k >> 4; c = k & 15; valid = (c < 10); }
        else     { k4 = 2; c = k; valid = (k < 10); }
        valid = valid && (n < COUT);
        float wv = 0.f;
        if (valid) {
            const int i1 = swap ? k3 : k1, i2 = swap ? k4 : k2;
            const int i3 = swap ? k1 : k3, i4 = swap ? k2 : k4;
            wv = W[(n * 10 + c) * 81 + ((i1 * 3 + i2) * 3 + i3) * 3 + i4];
        }
        us[j] = f2bf(wv);
    }
    u32* o = ft + (size_t)gid * 4;
    o[0] = (u32)us[0] | ((u32)us[1] << 16);
    o[1] = (u32)us[2] | ((u32)us[3] << 16);
    o[2] = (u32)us[4] | ((u32)us[5] << 16);
    o[3] = (u32)us[6] | ((u32)us[7] << 16);
}

// ---------------------------------------------------------------------------
// Zero the halo positions (h' in {0,31} or t' in {0,31}) of all 1800 planes
// of y1 and y2. Interiors (incl. c10..15) are written by conv1/convm2.
__global__ __launch_bounds__(128) void zerok(u16* __restrict__ y1, u16* __restrict__ y2)
{
    const int pb = blockIdx.x, tid = threadIdx.x;
    if (tid >= 124) return;
    int hp, tp;
    if (tid < 32)      { hp = 0;        tp = tid; }
    else if (tid < 64) { hp = 31;       tp = tid - 32; }
    else if (tid < 94) { hp = tid - 63; tp = 0; }
    else               { hp = tid - 93; tp = 31; }
    const size_t off = (size_t)pb * PLANE + hp * 1024 + tp * 32;
    const uint4 z = make_uint4(0, 0, 0, 0);
    *(uint4*)((char*)y1 + off)      = z;
    *(uint4*)((char*)y1 + off + 16) = z;
    *(uint4*)((char*)y2 + off)      = z;
    *(uint4*)((char*)y2 + off + 16) = z;
}

// ---------------------------------------------------------------------------
// Layer 1: Cin=1, one branch (10 couts), fp32 vector, writes padded-plane y1.
__global__ __launch_bounds__(256, 4) void conv1_k(
    const float* __restrict__ x, const float* __restrict__ w1,
    const float* __restrict__ b1, u16* __restrict__ y1buf, int swap)
{
    __shared__ float P[32 * 33];
    const int w1i = blockIdx.x, h1 = blockIdx.y, b = blockIdx.z;
    const int tid = threadIdx.x;

    int h2i[4], t4[4], posv[4];
    bool pv[4];
    float acc[4][10];
#pragma unroll
    for (int i = 0; i < 4; ++i) {
        int p = tid + i * 256;
        pv[i] = (p < S2);
        if (!pv[i]) p = S2 - 1;
        posv[i] = p; h2i[i] = p / S; t4[i] = p - h2i[i] * S;
#pragma unroll
        for (int co = 0; co < 10; ++co) acc[i][co] = 0.f;
    }
    for (int i = tid; i < 32 * 33; i += 256) P[i] = 0.f;

    for (int k12 = 0; k12 < 9; ++k12) {
        const int g1 = h1 + k12 / 3 - 1, g2 = w1i + k12 % 3 - 1;
        if (g1 < 0 || g1 >= S || g2 < 0 || g2 >= S) continue;
        __syncthreads();
        for (int idx = tid; idx < S2; idx += 256) {
            const int h = idx / S, t = idx - h * S;
            P[(h + 1) * 33 + (t + 1)] =
                x[(long)b * S4 + (long)(g1 * S + g2) * S2 + idx];
        }
        __syncthreads();
#pragma unroll
        for (int kk = 0; kk < 9; ++kk) {
            const int k3 = kk / 3, k4 = kk % 3;
            float wv[10];
#pragma unroll
            for (int co = 0; co < 10; ++co)
                wv[co] = swap ? w1[co * 81 + kk * 9 + k12]
                              : w1[co * 81 + k12 * 9 + kk];
#pragma unroll
            for (int i = 0; i < 4; ++i) {
                const float v = P[(h2i[i] + k3) * 33 + (t4[i] + k4)];
#pragma unroll
                for (int co = 0; co < 10; ++co)
                    acc[i][co] = fmaf(wv[co], v, acc[i][co]);
            }
        }
    }
    char* pl = (char*)y1buf + (size_t)(b * 900 + h1 * S + w1i) * PLANE;
#pragma unroll
    for (int i = 0; i < 4; ++i) {
        if (!pv[i]) continue;
        u16 c16[10];
#pragma unroll
        for (int co = 0; co < 10; ++co)
            c16[co] = f2bf(fmaxf(acc[i][co] + b1[co], 0.f));
        uint4 lo, hi;
        lo.x = (u32)c16[0] | ((u32)c16[1] << 16);
        lo.y = (u32)c16[2] | ((u32)c16[3] << 16);
        lo.z = (u32)c16[4] | ((u32)c16[5] << 16);
        lo.w = (u32)c16[6] | ((u32)c16[7] << 16);
        hi.x = (u32)c16[8] | ((u32)c16[9] << 16);
        hi.y = 0; hi.z = 0; hi.w = 0;
        char* a = pl + (h2i[i] + 1) * 1024 + (t4[i] + 1) * 32;
        *(uint4*)a = lo;
        *(uint4*)(a + 16) = hi;
    }
}

// ---------------------------------------------------------------------------
// Barrier-free MFMA conv. A-fragments loaded directly from padded planes.
// Per tile (16 t-rows x 16 couts, h2 = 2i+h0): 3 k3 x 2 tb = 6 MFMAs,
// fragments (h', tb) chained across tiles (k3=2 of tile i == k3=0 of i+1).
template<int COUT, bool ACCUM>
__global__ __launch_bounds__(256, 3) void convm_k(
    const u16* __restrict__ ybuf, const u32* __restrict__ ftab,
    const float* __restrict__ bias, void* __restrict__ outp)
{
    const int w1i = blockIdx.x, h1 = blockIdx.y, b = blockIdx.z;
    const int tid = threadIdx.x;
    const int lane = tid & 63, wv = tid >> 6;
    const int m = lane & 15, q = lane >> 4;
    const int t0 = (wv & 1) * 14, h0 = wv >> 1;
    const int laneoff = (t0 + m) * 32 + q * 16;    // bytes within h'-row

    f32x4 acc[15];
#pragma unroll
    for (int i = 0; i < 15; ++i) acc[i] = (f32x4){0.f, 0.f, 0.f, 0.f};

    int kl[9], nk = 0;
    for (int k12 = 0; k12 < 9; ++k12) {
        const int g1 = h1 + k12 / 3 - 1, g2 = w1i + k12 % 3 - 1;
        if (g1 >= 0 && g1 < S && g2 >= 0 && g2 < S)
            kl[nk++] = (g1 * S + g2) | (k12 << 10);
    }

    const char* Y = (const char*)ybuf + (size_t)b * 900 * PLANE;
    const uint4* ft4 = (const uint4*)ftab;

    uint4 bfr[6];
    {
        const int k12 = kl[0] >> 10;
#pragma unroll
        for (int f = 0; f < 6; ++f)
            bfr[f] = ft4[(k12 * 6 + f) * 64 + lane];
    }

    for (int ki = 0; ki < nk; ++ki) {
        const char* P = Y + (size_t)(kl[ki] & 0x3ff) * PLANE + laneoff;
        uint4 bnx[6];
        {
            const int k12n = kl[(ki + 1 < nk) ? (ki + 1) : ki] >> 10;
#pragma unroll
            for (int f = 0; f < 6; ++f)
                bnx[f] = ft4[(k12n * 6 + f) * 64 + lane];
        }
        const char* rp = P + h0 * 1024;
        uint4 f0 = *(const uint4*)rp;
        uint4 f1 = *(const uint4*)(rp + 64);
#pragma unroll
        for (int i = 0; i < 15; ++i) {
            const char* row = P + (2 * i + h0) * 1024;
            const uint4 g0 = *(const uint4*)(row + 1024);
            const uint4 g1v = *(const uint4*)(row + 1024 + 64);
            const uint4 e0 = *(const uint4*)(row + 2048);
            const uint4 e1 = *(const uint4*)(row + 2048 + 64);
            acc[i] = __builtin_amdgcn_mfma_f32_16x16x32_bf16(
                __builtin_bit_cast(bf16x8, f0), __builtin_bit_cast(bf16x8, bfr[0]), acc[i], 0, 0, 0);
            acc[i] = __builtin_amdgcn_mfma_f32_16x16x32_bf16(
                __builtin_bit_cast(bf16x8, f1), __builtin_bit_cast(bf16x8, bfr[1]), acc[i], 0, 0, 0);
            acc[i] = __builtin_amdgcn_mfma_f32_16x16x32_bf16(
                __builtin_bit_cast(bf16x8, g0), __builtin_bit_cast(bf16x8, bfr[2]), acc[i], 0, 0, 0);
            acc[i] = __builtin_amdgcn_mfma_f32_16x16x32_bf16(
                __builtin_bit_cast(bf16x8, g1v), __builtin_bit_cast(bf16x8, bfr[3]), acc[i], 0, 0, 0);
            acc[i] = __builtin_amdgcn_mfma_f32_16x16x32_bf16(
                __builtin_bit_cast(bf16x8, e0), __builtin_bit_cast(bf16x8, bfr[4]), acc[i], 0, 0, 0);
            acc[i] = __builtin_amdgcn_mfma_f32_16x16x32_bf16(
                __builtin_bit_cast(bf16x8, e1), __builtin_bit_cast(bf16x8, bfr[5]), acc[i], 0, 0, 0);
            f0 = e0; f1 = e1;
        }
#pragma unroll
        for (int f = 0; f < 6; ++f) bfr[f] = bnx[f];
    }

    // epilogue: C lane holds row (4q+r) = t offset, col n = cout
    const int n = lane & 15;
    const float bv = (n < COUT) ? bias[n] : 0.f;
    if (COUT == 10) {
        char* pl = (char*)outp + (size_t)(b * 900 + h1 * S + w1i) * PLANE;
#pragma unroll
        for (int i = 0; i < 15; ++i) {
            const int h2 = 2 * i + h0;
#pragma unroll
            for (int r = 0; r < 4; ++r) {
                const int mrow = 4 * q + r;
                if (t0 && mrow < 2) continue;      // t=14,15 owned by t0=0 tiles
                const int t = t0 + mrow;
                const float v = (n < 10) ? fmaxf(acc[i][r] + bv, 0.f) : 0.f;
                *(u16*)(pl + (h2 + 1) * 1024 + (t + 1) * 32 + n * 2) = f2bf(v);
            }
        }
    } else {
        const long plane = (long)(h1 * S + w1i) * S2;
#pragma unroll
        for (int i = 0; i < 15; ++i) {
            const int h2 = 2 * i + h0;
#pragma unroll
            for (int r = 0; r < 4; ++r) {
                const int mrow = 4 * q + r;
                if (t0 && mrow < 2) continue;
                if (n != 0) continue;
                const int t = t0 + mrow;
                const float v = fmaxf(acc[i][r] + bv, 0.f);
                float* o = (float*)outp + (size_t)b * S4 + plane + h2 * S + t;
                if (ACCUM) *o += v; else *o = v;
            }
        }
    }
}

// ---------------------------------------------------------------------------
extern "C" void kernel_launch(void* const* d_in, const int* in_sizes, int n_in,
                              void* d_out, int out_size, void* d_ws, size_t ws_size,
                              hipStream_t stream)
{
    const float* x   = (const float*)d_in[0];
    const float* w1p = (const float*)d_in[1];
    const float* b1p = (const float*)d_in[2];
    const float* w2p = (const float*)d_in[3];
    const float* b2p = (const float*)d_in[4];
    const float* w3p = (const float*)d_in[5];
    const float* b3p = (const float*)d_in[6];
    float* out = (float*)d_out;

    // ws: fragtab 13824 uint4 = 221184 B | y1 59.0 MB | y2 59.0 MB (+ tail pad)
    u32* ft = (u32*)d_ws;
    u16* y1 = (u16*)((char*)d_ws + 221184);
    u16* y2 = (u16*)((char*)y1 + YBYTES);

    fragprep_k<<<54, 256, 0, stream>>>(ft, w2p, w3p);
    zerok<<<1800, 128, 0, stream>>>(y1, y2);

    dim3 grid(S, S, 2), blk(256);
    for (int br = 0; br < 2; ++br) {
        const u32* ft2 = ft + (size_t)br * 3456 * 4;        // set br
        const u32* ft3 = ft + (size_t)(2 + br) * 3456 * 4;  // set 2+br
        conv1_k<<<grid, blk, 0, stream>>>(x, w1p, b1p, y1, br);
        convm_k<10, false><<<grid, blk, 0, stream>>>(y1, ft2, b2p, (void*)y2);
        if (br == 0)
            convm_k<1, false><<<grid, blk, 0, stream>>>(y2, ft3, b3p, (void*)out);
        else
            convm_k<1, true><<<grid, blk, 0, stream>>>(y2, ft3, b3p, (void*)out);
    }
}

// Round 7
// 589.910 us; speedup vs baseline: 1.6087x; 1.6087x over previous
//
#include <hip/hip_runtime.h>

// 4D conv net, MI355X. S=30, B=2, ch 1->10->10->1, kernel 3^4, pad 1, ReLU.
// out = net(x,w) + net(x,w_swap), w_swap has (k1,k2)<->(k3,k4).
// R7: all layers as 32x32x16 bf16 MFMA, M = 32 padded t-positions (full row),
// K = 16 channels, N = k4*10+co (30/32 cols). One b128 A-read per h2-row
// (k3-chained), ~6 loads per wave-k12. Cross-k4 combine once in epilogue via
// per-wave LDS transpose. Main loop barrier-free; activations in padded
// planes [h'(32)][t'(32)][c(16)] bf16.

static constexpr int S  = 30;
static constexpr long S4 = 810000;
static constexpr size_t PLANE = 32768;                  // 32*32*16*2 B
static constexpr size_t YBYTES = (size_t)1800 * PLANE;  // [b(2)][g1][g2]

typedef __bf16 bf16x8 __attribute__((ext_vector_type(8)));
typedef float  f32x16 __attribute__((ext_vector_type(16)));
typedef unsigned int  u32;
typedef unsigned short u16;

static __device__ __forceinline__ u16 f2bf(float f) {
    u32 u = __builtin_bit_cast(u32, f);
    return (u16)((u + 0x7fffu + ((u >> 16) & 1u)) >> 16);
}

// ---------------------------------------------------------------------------
// B-fragment table: [set(6)][k12(9)][k3(3)][lane(64)] uint4.
// set = layer*2 + branch. Layer 0: w1 (K slot 0 only); 1: w2 (K = c, 10/16);
// 2: w3 (K = c, cols {0,10,20} only). N: n = k4*10 + co (n<30).
// B[k][n]: lane = n + 32*hl holds k = hl*8 + j.
__global__ __launch_bounds__(256) void fragprep_k(u32* __restrict__ ft,
    const float* __restrict__ w1, const float* __restrict__ w2,
    const float* __restrict__ w3)
{
    const int gid = blockIdx.x * 256 + threadIdx.x;
    if (gid >= 6 * 27 * 64) return;
    const int lane = gid & 63;
    int r = gid >> 6;
    const int k3 = r % 3; r /= 3;
    const int k12 = r % 9; const int set = r / 9;
    const int layer = set >> 1, swap = set & 1;
    const int k1 = k12 / 3, k2 = k12 % 3;
    const int n = lane & 31, hl = lane >> 5;

    u16 us[8];
#pragma unroll
    for (int j = 0; j < 8; ++j) us[j] = 0;
    if (n < 30) {
        const int k4 = (n < 10) ? 0 : ((n < 20) ? 1 : 2);
        const int co = n - 10 * k4;
        const int i1 = swap ? k3 : k1, i2 = swap ? k4 : k2;
        const int i3 = swap ? k1 : k3, i4 = swap ? k2 : k4;
        const int widx = ((i1 * 3 + i2) * 3 + i3) * 3 + i4;
#pragma unroll
        for (int j = 0; j < 8; ++j) {
            const int k = hl * 8 + j;
            float wv = 0.f;
            if (layer == 0) { if (k == 0) wv = w1[co * 81 + widx]; }
            else if (layer == 1) { if (k < 10) wv = w2[(co * 10 + k) * 81 + widx]; }
            else { if (k < 10 && co == 0) wv = w3[k * 81 + widx]; }
            us[j] = f2bf(wv);
        }
    }
    u32* o = ft + (size_t)gid * 4;
    o[0] = (u32)us[0] | ((u32)us[1] << 16);
    o[1] = (u32)us[2] | ((u32)us[3] << 16);
    o[2] = (u32)us[4] | ((u32)us[5] << 16);
    o[3] = (u32)us[6] | ((u32)us[7] << 16);
}

// ---------------------------------------------------------------------------
// Zero halo positions (h' or t' in {0,31}) of all 1800 planes of y1 and y2.
// Interior c10..15 never needs zeroing: B-table has zero weights for k>=10.
__global__ __launch_bounds__(128) void zerok(u16* __restrict__ y1, u16* __restrict__ y2)
{
    const int pb = blockIdx.x, tid = threadIdx.x;
    if (tid >= 124) return;
    int hp, tp;
    if (tid < 32)      { hp = 0;        tp = tid; }
    else if (tid < 64) { hp = 31;       tp = tid - 32; }
    else if (tid < 94) { hp = tid - 63; tp = 0; }
    else               { hp = tid - 93; tp = 31; }
    const size_t off = (size_t)pb * PLANE + hp * 1024 + tp * 32;
    const uint4 z = make_uint4(0, 0, 0, 0);
    *(uint4*)((char*)y1 + off)      = z;
    *(uint4*)((char*)y1 + off + 16) = z;
    *(uint4*)((char*)y2 + off)      = z;
    *(uint4*)((char*)y2 + off + 16) = z;
}

// ---------------------------------------------------------------------------
// Unified conv layer. Block = (w1, h1, z) with z = b*2 + half; block computes
// h2 rows [half*15, half*15+15). Wave wv owns 4 rows (wave 3: 3).
// LAYER 0: in = x fp32 (bf16-cast in register, K slot 0).
// LAYER 1: in = y1 padded planes, out = y2 padded planes.
// LAYER 2: in = y2, out = fp32 d_out (ACCUM adds for branch 1).
template<int LAYER, bool ACCUM>
__global__ __launch_bounds__(256, 3) void conv_k(
    const void* __restrict__ inp, const u32* __restrict__ ftab,
    const float* __restrict__ bias, void* __restrict__ outp)
{
    __shared__ float E[4][1056];          // per-wave 32 cols x 33-stride rows
    const int w1i = blockIdx.x, h1 = blockIdx.y;
    const int b = blockIdx.z >> 1, half = blockIdx.z & 1;
    const int tid = threadIdx.x;
    const int lane = tid & 63, wv = tid >> 6;
    const int m = lane & 31, hl = lane >> 5;    // A: row m = padded t', k-group hl
    const int rbase = half * 15 + wv * 4;
    const int rcnt = (wv == 3) ? 3 : 4;

    f32x16 acc[4];
#pragma unroll
    for (int r = 0; r < 4; ++r)
#pragma unroll
        for (int e = 0; e < 16; ++e) acc[r][e] = 0.f;

    int kl[9], nk = 0;
    for (int k12 = 0; k12 < 9; ++k12) {
        const int g1 = h1 + k12 / 3 - 1, g2 = w1i + k12 % 3 - 1;
        if (g1 >= 0 && g1 < S && g2 >= 0 && g2 < S)
            kl[nk++] = (g1 * S + g2) | (k12 << 10);
    }

    const uint4* ft4 = (const uint4*)ftab;
    uint4 B[3];
    {
        const int k0 = kl[0] >> 10;
#pragma unroll
        for (int f = 0; f < 3; ++f) B[f] = ft4[(k0 * 3 + f) * 64 + lane];
    }

    for (int ki = 0; ki < nk; ++ki) {
        const int g = kl[ki] & 1023;
        uint4 F[6];
        if (LAYER == 0) {
            const float* xp = (const float*)inp + ((size_t)b * 900 + g) * 900;
#pragma unroll
            for (int f = 0; f < 6; ++f) {
                if (f > rcnt + 1) continue;
                const int hp = rbase + f;            // h' = h2 + k3
                float v = 0.f;
                if (hl == 0 && hp >= 1 && hp <= 30 && m >= 1 && m <= 30)
                    v = xp[(hp - 1) * 30 + (m - 1)];
                F[f] = make_uint4((u32)f2bf(v), 0u, 0u, 0u);
            }
        } else {
            const char* P = (const char*)inp + ((size_t)b * 900 + g) * PLANE
                            + m * 32 + hl * 16;
#pragma unroll
            for (int f = 0; f < 6; ++f) {
                if (f > rcnt + 1) continue;
                F[f] = *(const uint4*)(P + (size_t)(rbase + f) * 1024);
            }
        }
        uint4 Bn[3];
        {
            const int kn = kl[(ki + 1 < nk) ? ki + 1 : ki] >> 10;
#pragma unroll
            for (int f = 0; f < 3; ++f) Bn[f] = ft4[(kn * 3 + f) * 64 + lane];
        }
#pragma unroll
        for (int r = 0; r < 4; ++r) {
            if (r >= rcnt) continue;                 // wave-uniform
            acc[r] = __builtin_amdgcn_mfma_f32_32x32x16_bf16(
                __builtin_bit_cast(bf16x8, F[r]),     __builtin_bit_cast(bf16x8, B[0]), acc[r], 0, 0, 0);
            acc[r] = __builtin_amdgcn_mfma_f32_32x32x16_bf16(
                __builtin_bit_cast(bf16x8, F[r + 1]), __builtin_bit_cast(bf16x8, B[1]), acc[r], 0, 0, 0);
            acc[r] = __builtin_amdgcn_mfma_f32_32x32x16_bf16(
                __builtin_bit_cast(bf16x8, F[r + 2]), __builtin_bit_cast(bf16x8, B[2]), acc[r], 0, 0, 0);
        }
        B[0] = Bn[0]; B[1] = Bn[1]; B[2] = Bn[2];
    }

    // Epilogue: per tile, transpose P through per-wave LDS, combine k4 shifts:
    // out[t][co] = sum_k4 P[t+k4][k4*10+co]. C/D: col = lane&31,
    // row = (reg&3) + 8*(reg>>2) + 4*hl.
    float* Ew = E[wv];
    for (int r = 0; r < 4; ++r) {
        const bool act = (r < rcnt);
        if (act) {
#pragma unroll
            for (int gq = 0; gq < 4; ++gq)
#pragma unroll
                for (int r4 = 0; r4 < 4; ++r4)
                    Ew[m * 33 + 4 * hl + 8 * gq + r4] = acc[r][gq * 4 + r4];
        }
        __syncthreads();
        if (act) {
            const int h2 = rbase + r;
            if (LAYER <= 1) {
                char* pl = (char*)outp + ((size_t)b * 900 + h1 * S + w1i) * PLANE
                           + (size_t)(h2 + 1) * 1024;
#pragma unroll
                for (int s = 0; s < 3; ++s) {
                    const int o = lane + 64 * s;
                    if (o >= 150) continue;
                    const int t = o / 5, cp = o - 5 * t;
                    const int c0 = 2 * cp, c1 = 2 * cp + 1;
                    float v0 = Ew[c0 * 33 + t] + Ew[(10 + c0) * 33 + t + 1]
                             + Ew[(20 + c0) * 33 + t + 2] + bias[c0];
                    float v1 = Ew[c1 * 33 + t] + Ew[(10 + c1) * 33 + t + 1]
                             + Ew[(20 + c1) * 33 + t + 2] + bias[c1];
                    v0 = fmaxf(v0, 0.f); v1 = fmaxf(v1, 0.f);
                    *(u32*)(pl + (t + 1) * 32 + cp * 4) =
                        (u32)f2bf(v0) | ((u32)f2bf(v1) << 16);
                }
            } else {
                if (lane < 30) {
                    const int t = lane;
                    float v = Ew[t] + Ew[330 + t + 1] + Ew[660 + t + 2] + bias[0];
                    v = fmaxf(v, 0.f);
                    float* o = (float*)outp + (size_t)b * S4
                               + (size_t)(h1 * S + w1i) * 900 + h2 * 30 + t;
                    if (ACCUM) *o += v; else *o = v;
                }
            }
        }
        __syncthreads();
    }
}

// ---------------------------------------------------------------------------
extern "C" void kernel_launch(void* const* d_in, const int* in_sizes, int n_in,
                              void* d_out, int out_size, void* d_ws, size_t ws_size,
                              hipStream_t stream)
{
    const float* x   = (const float*)d_in[0];
    const float* w1p = (const float*)d_in[1];
    const float* b1p = (const float*)d_in[2];
    const float* w2p = (const float*)d_in[3];
    const float* b2p = (const float*)d_in[4];
    const float* w3p = (const float*)d_in[5];
    const float* b3p = (const float*)d_in[6];
    float* out = (float*)d_out;

    // ws: fragtab 6*27*64 uint4 = 165888 B | y1 59 MB | y2 59 MB
    u32* ft = (u32*)d_ws;
    u16* y1 = (u16*)((char*)d_ws + 165888);
    u16* y2 = (u16*)((char*)y1 + YBYTES);

    fragprep_k<<<41, 256, 0, stream>>>(ft, w1p, w2p, w3p);
    zerok<<<1800, 128, 0, stream>>>(y1, y2);

    dim3 grid(S, S, 4), blk(256);
    for (int br = 0; br < 2; ++br) {
        const u32* f1 = ft + (size_t)(0 + br) * 27 * 64 * 4;
        const u32* f2 = ft + (size_t)(2 + br) * 27 * 64 * 4;
        const u32* f3 = ft + (size_t)(4 + br) * 27 * 64 * 4;
        conv_k<0, false><<<grid, blk, 0, stream>>>(x,  f1, b1p, (void*)y1);
        conv_k<1, false><<<grid, blk, 0, stream>>>(y1, f2, b2p, (void*)y2);
        if (br == 0)
            conv_k<2, false><<<grid, blk, 0, stream>>>(y2, f3, b3p, (void*)out);
        else
            conv_k<2, true><<<grid, blk, 0, stream>>>(y2, f3, b3p, (void*)out);
    }
}